// Round 4
// baseline (268.252 us; speedup 1.0000x reference)
//
#include <hip/hip_runtime.h>
#include <math.h>

#define N_NODES 50000
#define N_EDGES 400000
#define NB_SCAN 196   // ceil(50000/256)

typedef __attribute__((ext_vector_type(8))) short bf16x8;
typedef __attribute__((ext_vector_type(4))) float f32x4;

__device__ __forceinline__ float lrelu(float x){ return x > 0.f ? x : 0.2f*x; }
__device__ __forceinline__ float bf2f(unsigned short u){ return __uint_as_float(((unsigned int)u)<<16); }
__device__ __forceinline__ unsigned short f2bf(float f){
    unsigned int b = __float_as_uint(f);
    return (unsigned short)((b + 0x7FFFu + ((b>>16)&1u)) >> 16);   // RNE
}
__device__ __forceinline__ void bf8_unpack(uint4 u, float f[8]){
    f[0] = __uint_as_float(u.x << 16);
    f[1] = __uint_as_float(u.x & 0xFFFF0000u);
    f[2] = __uint_as_float(u.y << 16);
    f[3] = __uint_as_float(u.y & 0xFFFF0000u);
    f[4] = __uint_as_float(u.z << 16);
    f[5] = __uint_as_float(u.z & 0xFFFF0000u);
    f[6] = __uint_as_float(u.w << 16);
    f[7] = __uint_as_float(u.w & 0xFFFF0000u);
}

// ---------------- CSR build ----------------
__global__ void hist_k(const int* __restrict__ dst, int* __restrict__ counts){
    int e = blockIdx.x*256 + threadIdx.x;
    if (e < N_EDGES) atomicAdd(&counts[dst[e]], 1);
}

__global__ void breduce_k(const int* __restrict__ counts, int* __restrict__ bsum){
    __shared__ int s[256];
    int i = blockIdx.x*256 + threadIdx.x;
    int v = (i < N_NODES) ? counts[i] : 0;
    s[threadIdx.x] = v; __syncthreads();
    for (int d = 128; d > 0; d >>= 1){
        if (threadIdx.x < d) s[threadIdx.x] += s[threadIdx.x + d];
        __syncthreads();
    }
    if (threadIdx.x == 0) bsum[blockIdx.x] = s[0];
}

__global__ void bscan_k(const int* __restrict__ bsum, int* __restrict__ bscan){
    __shared__ int s[256];
    int t = threadIdx.x;
    int v = (t < NB_SCAN) ? bsum[t] : 0;
    s[t] = v; __syncthreads();
    for (int d = 1; d < 256; d <<= 1){
        int x = (t >= d) ? s[t-d] : 0;
        __syncthreads();
        s[t] += x;
        __syncthreads();
    }
    if (t < NB_SCAN) bscan[t] = s[t] - v;   // exclusive
}

__global__ void scanfinal_k(const int* __restrict__ counts, const int* __restrict__ bscan,
                            int* __restrict__ offsets, int* __restrict__ cursor){
    __shared__ int s[256];
    int t = threadIdx.x; int i = blockIdx.x*256 + t;
    int v = (i < N_NODES) ? counts[i] : 0;
    s[t] = v; __syncthreads();
    for (int d = 1; d < 256; d <<= 1){
        int x = (t >= d) ? s[t-d] : 0;
        __syncthreads();
        s[t] += x;
        __syncthreads();
    }
    if (i < N_NODES){
        int off = s[t] - v + bscan[blockIdx.x];
        offsets[i] = off; cursor[i] = off;
    }
}

__global__ void scatter_k(const int* __restrict__ src, const int* __restrict__ dst,
                          int* __restrict__ cursor, int* __restrict__ csr_src){
    int e = blockIdx.x*256 + threadIdx.x;
    if (e < N_EDGES){
        int d = dst[e];
        int pos = atomicAdd(&cursor[d], 1);
        csr_src[pos] = src[e];
    }
}

// ---------------- weight/att casts & packs ----------------
// W1T[n][k] = W1[k][n] (256x128);  WmlT[n][k] = {W_mu|W_ls}[k][n] (128x256)
// attS2 = [att_src_mu | att_src_ls], attD2 likewise (128 floats each)
__global__ void cast_w_k(const float* __restrict__ W1,
                         const float* __restrict__ Wmu, const float* __restrict__ Wls,
                         const float* __restrict__ asmu, const float* __restrict__ asls,
                         const float* __restrict__ admu, const float* __restrict__ adls,
                         unsigned short* __restrict__ W1T, unsigned short* __restrict__ WmlT,
                         float* __restrict__ attS2, float* __restrict__ attD2){
    int i = blockIdx.x*256 + threadIdx.x;
    if (i < 32768){
        int n = i >> 7, k = i & 127;
        W1T[i] = f2bf(W1[k*256 + n]);
        int n2 = i >> 8, k2 = i & 255;
        float v = (n2 < 64) ? Wmu[k2*64 + n2] : Wls[k2*64 + (n2-64)];
        WmlT[i] = f2bf(v);
    }
    if (blockIdx.x == 0 && threadIdx.x < 128){
        int t = threadIdx.x;
        attS2[t] = (t < 64) ? asmu[t] : asls[t-64];
        attD2[t] = (t < 64) ? admu[t] : adls[t-64];
    }
}

// ---------------- bf16 MFMA GEMM with fused attention-logit epilogue ----------------
// C[M x N] = A[M x K] @ BT[N x K]^T.  128x128 tile, BK=32, 256 thr (4 waves 2x2).
// Epilogue: atomicAdd per-row dot(h_row, attS/attD) into asf/adf (float2 per node,
// component = (col0+wx*64)>>grp_shift).
template<bool AF32>
__global__ __launch_bounds__(256) void mfma_gemm_k(const void* __restrict__ Av,
        const unsigned short* __restrict__ BT, unsigned short* __restrict__ C,
        int M, int K, int ldc,
        const float* __restrict__ attS, const float* __restrict__ attD,
        float* __restrict__ asf, float* __restrict__ adf, int grp_shift){
    __shared__ unsigned short As[128*40];   // +8 pad
    __shared__ unsigned short Bs[128*40];
    int t = threadIdx.x;
    int lane = t & 63, wid = t >> 6;
    int wy = wid >> 1, wx = wid & 1;
    int quad = lane >> 4, l15 = lane & 15;
    int row0 = blockIdx.y * 128;
    int col0 = blockIdx.x * 128;

    f32x4 acc[4][4];
    #pragma unroll
    for (int i = 0; i < 4; i++)
        #pragma unroll
        for (int j = 0; j < 4; j++)
            acc[i][j] = (f32x4){0.f, 0.f, 0.f, 0.f};

    int r = t >> 2;              // 0..63
    int cofs = (t & 3) * 8;      // elem offset in k-slice

    for (int k0 = 0; k0 < K; k0 += 32){
        int gr0 = min(row0 + r,      M-1);
        int gr1 = min(row0 + r + 64, M-1);
        uint4 av0, av1;
        if (AF32){
            const float* A = (const float*)Av;
            float f0[8], f1[8];
            *(float4*)&f0[0] = *(const float4*)(A + (size_t)gr0*K + k0 + cofs);
            *(float4*)&f0[4] = *(const float4*)(A + (size_t)gr0*K + k0 + cofs + 4);
            *(float4*)&f1[0] = *(const float4*)(A + (size_t)gr1*K + k0 + cofs);
            *(float4*)&f1[4] = *(const float4*)(A + (size_t)gr1*K + k0 + cofs + 4);
            av0.x = f2bf(f0[0]) | ((unsigned)f2bf(f0[1])<<16);
            av0.y = f2bf(f0[2]) | ((unsigned)f2bf(f0[3])<<16);
            av0.z = f2bf(f0[4]) | ((unsigned)f2bf(f0[5])<<16);
            av0.w = f2bf(f0[6]) | ((unsigned)f2bf(f0[7])<<16);
            av1.x = f2bf(f1[0]) | ((unsigned)f2bf(f1[1])<<16);
            av1.y = f2bf(f1[2]) | ((unsigned)f2bf(f1[3])<<16);
            av1.z = f2bf(f1[4]) | ((unsigned)f2bf(f1[5])<<16);
            av1.w = f2bf(f1[6]) | ((unsigned)f2bf(f1[7])<<16);
        } else {
            const unsigned short* A = (const unsigned short*)Av;
            av0 = *(const uint4*)(A + (size_t)gr0*K + k0 + cofs);
            av1 = *(const uint4*)(A + (size_t)gr1*K + k0 + cofs);
        }
        uint4 bv0 = *(const uint4*)(BT + (size_t)(col0 + r)*K      + k0 + cofs);
        uint4 bv1 = *(const uint4*)(BT + (size_t)(col0 + r + 64)*K + k0 + cofs);
        __syncthreads();
        *(uint4*)&As[r*40 + cofs]      = av0;
        *(uint4*)&As[(r+64)*40 + cofs] = av1;
        *(uint4*)&Bs[r*40 + cofs]      = bv0;
        *(uint4*)&Bs[(r+64)*40 + cofs] = bv1;
        __syncthreads();

        bf16x8 af[4], bf[4];
        #pragma unroll
        for (int i = 0; i < 4; i++)
            af[i] = *(const bf16x8*)&As[(wy*64 + i*16 + l15)*40 + quad*8];
        #pragma unroll
        for (int j = 0; j < 4; j++)
            bf[j] = *(const bf16x8*)&Bs[(wx*64 + j*16 + l15)*40 + quad*8];
        #pragma unroll
        for (int i = 0; i < 4; i++)
            #pragma unroll
            for (int j = 0; j < 4; j++)
                acc[i][j] = __builtin_amdgcn_mfma_f32_16x16x32_bf16(af[i], bf[j], acc[i][j], 0, 0, 0);
    }

    // C store: C/D layout col=lane&15, row=quad*4+reg  [m89-verified]
    #pragma unroll
    for (int i = 0; i < 4; i++){
        #pragma unroll
        for (int reg = 0; reg < 4; reg++){
            int rr = row0 + wy*64 + i*16 + quad*4 + reg;
            if (rr < M){
                #pragma unroll
                for (int j = 0; j < 4; j++){
                    int cc = col0 + wx*64 + j*16 + l15;
                    C[(size_t)rr*ldc + cc] = f2bf(acc[i][j][reg]);
                }
            }
        }
    }

    // fused attention-logit dots
    float attsj[4], attdj[4];
    #pragma unroll
    for (int j = 0; j < 4; j++){
        int cc = col0 + wx*64 + j*16 + l15;
        attsj[j] = attS[cc]; attdj[j] = attD[cc];
    }
    int grp = (col0 + wx*64) >> grp_shift;
    #pragma unroll
    for (int i = 0; i < 4; i++){
        #pragma unroll
        for (int reg = 0; reg < 4; reg++){
            float p = 0.f, q = 0.f;
            #pragma unroll
            for (int j = 0; j < 4; j++){
                float v = acc[i][j][reg];
                p = fmaf(v, attsj[j], p);
                q = fmaf(v, attdj[j], q);
            }
            #pragma unroll
            for (int o = 8; o; o >>= 1){
                p += __shfl_down(p, o, 16);
                q += __shfl_down(q, o, 16);
            }
            int rr = row0 + wy*64 + i*16 + quad*4 + reg;
            if (l15 == 0 && rr < M){
                atomicAdd(asf + 2*(size_t)rr + grp, p);
                atomicAdd(adf + 2*(size_t)rr + grp, q);
            }
        }
    }
}

// ---------------- conv1 aggregation: 2 nodes/wave, ushort8 lanes, branchless ----------------
// block 256 = 4 waves = 8 nodes; grid 6250 (exact). lane: half=lane>>5 node, l32 owns 8 ch.
__global__ __launch_bounds__(256) void agg1_k(const unsigned short* __restrict__ h1,
        const float2* __restrict__ as, const float2* __restrict__ ad,
        const int* __restrict__ counts, const int* __restrict__ offsets,
        const int* __restrict__ csr_src,
        const float* __restrict__ b1, unsigned short* __restrict__ hout){
    int wave = threadIdx.x >> 6, lane = threadIdx.x & 63;
    int half = lane >> 5, l32 = lane & 31;
    int n = blockIdx.x*8 + wave*2 + half;
    int head = l32 >> 4;
    const uint4* h1v = (const uint4*)h1;   // 16B = 8 bf16; 32 uint4 per row

    float2 adn = ad[n], asn = as[n];
    float adh = head ? adn.y : adn.x;
    float ash = head ? asn.y : asn.x;
    float m = lrelu(ash + adh), l = 1.f;

    float acc[8];
    bf8_unpack(h1v[(size_t)n*32 + l32], acc);

    int off = offsets[n], deg = counts[n];
    int dmax = max(deg, __shfl(deg, lane ^ 32));

    for (int k = 0; k < dmax; k += 4){
        int   sx[4]; float ex[4]; uint4 rx[4];
        #pragma unroll
        for (int u = 0; u < 4; u++){
            bool v = (k+u) < deg;
            sx[u] = v ? csr_src[off+k+u] : n;
            float2 a2 = as[sx[u]];
            ex[u] = v ? lrelu((head ? a2.y : a2.x) + adh) : -1e30f;
            rx[u] = h1v[(size_t)sx[u]*32 + l32];
        }
        #pragma unroll
        for (int u = 0; u < 4; u++){
            float nm = fmaxf(m, ex[u]);
            float sc = __expf(m - nm);
            float w  = __expf(ex[u] - nm);
            l = l*sc + w;
            float rf[8]; bf8_unpack(rx[u], rf);
            #pragma unroll
            for (int c = 0; c < 8; c++)
                acc[c] = fmaf(acc[c], sc, w*rf[c]);
            m = nm;
        }
    }

    float invl = 1.f / (l + 1e-16f);
    int cbase = l32*8;
    float bb[8];
    *(float4*)&bb[0] = *(const float4*)&b1[cbase];
    *(float4*)&bb[4] = *(const float4*)&b1[cbase+4];
    unsigned short ob[8];
    #pragma unroll
    for (int c = 0; c < 8; c++){
        float v = acc[c]*invl + bb[c];
        v = v > 0.f ? v : __expf(v) - 1.f;
        ob[c] = f2bf(v);
    }
    uint4 o;
    o.x = ob[0] | ((unsigned)ob[1]<<16);
    o.y = ob[2] | ((unsigned)ob[3]<<16);
    o.z = ob[4] | ((unsigned)ob[5]<<16);
    o.w = ob[6] | ((unsigned)ob[7]<<16);
    ((uint4*)hout)[(size_t)n*32 + l32] = o;
}

// ---------------- conv_mu/ls aggregation: 4 nodes/wave, 16 lanes each, branchless ----------------
// block 256 = 16 nodes; grid 3125 (exact). l16 owns 8 ch of 128; g = l16>>3 (0=mu,1=ls)
__global__ __launch_bounds__(256) void agg2_k(const unsigned short* __restrict__ hml,
        const float2* __restrict__ as, const float2* __restrict__ ad,
        const int* __restrict__ counts, const int* __restrict__ offsets,
        const int* __restrict__ csr_src,
        const float* __restrict__ b_mu, const float* __restrict__ b_ls,
        float* __restrict__ out){
    int wave = threadIdx.x >> 6, lane = threadIdx.x & 63;
    int grp4 = lane >> 4, l16 = lane & 15;
    int n = blockIdx.x*16 + wave*4 + grp4;
    int g = l16 >> 3;
    const uint4* hv = (const uint4*)hml;   // 16 uint4 per row

    float2 adn = ad[n], asn = as[n];
    float adh = g ? adn.y : adn.x;
    float ash = g ? asn.y : asn.x;
    float m = lrelu(ash + adh), l = 1.f;

    float acc[8];
    bf8_unpack(hv[(size_t)n*16 + l16], acc);

    int off = offsets[n], deg = counts[n];
    int dm = max(deg, __shfl_xor(deg, 16));
    int dmax = max(dm, __shfl_xor(dm, 32));

    for (int k = 0; k < dmax; k += 4){
        int   sx[4]; float ex[4]; uint4 rx[4];
        #pragma unroll
        for (int u = 0; u < 4; u++){
            bool v = (k+u) < deg;
            sx[u] = v ? csr_src[off+k+u] : n;
            float2 a2 = as[sx[u]];
            ex[u] = v ? lrelu((g ? a2.y : a2.x) + adh) : -1e30f;
            rx[u] = hv[(size_t)sx[u]*16 + l16];
        }
        #pragma unroll
        for (int u = 0; u < 4; u++){
            float nm = fmaxf(m, ex[u]);
            float sc = __expf(m - nm);
            float w  = __expf(ex[u] - nm);
            l = l*sc + w;
            float rf[8]; bf8_unpack(rx[u], rf);
            #pragma unroll
            for (int c = 0; c < 8; c++)
                acc[c] = fmaf(acc[c], sc, w*rf[c]);
            m = nm;
        }
    }

    float invl = 1.f / (l + 1e-16f);
    int c0 = (l16 & 7) * 8;               // channel within this output's 64
    const float* bb = g ? b_ls : b_mu;
    float* base = g ? (out + (size_t)N_NODES*64) : out;
    float ov[8];
    #pragma unroll
    for (int c = 0; c < 8; c++) ov[c] = acc[c]*invl + bb[c0+c];
    *(float4*)&base[(size_t)n*64 + c0]     = *(float4*)&ov[0];
    *(float4*)&base[(size_t)n*64 + c0 + 4] = *(float4*)&ov[4];
}

extern "C" void kernel_launch(void* const* d_in, const int* in_sizes, int n_in,
                              void* d_out, int out_size, void* d_ws, size_t ws_size,
                              hipStream_t stream) {
    const float* x           = (const float*)d_in[0];
    const int*   ei          = (const int*)d_in[1];
    const float* W1          = (const float*)d_in[2];
    const float* att_src1    = (const float*)d_in[3];
    const float* att_dst1    = (const float*)d_in[4];
    const float* b1          = (const float*)d_in[5];
    const float* W_mu        = (const float*)d_in[6];
    const float* att_src_mu  = (const float*)d_in[7];
    const float* att_dst_mu  = (const float*)d_in[8];
    const float* b_mu        = (const float*)d_in[9];
    const float* W_ls        = (const float*)d_in[10];
    const float* att_src_ls  = (const float*)d_in[11];
    const float* att_dst_ls  = (const float*)d_in[12];
    const float* b_ls        = (const float*)d_in[13];
    float* out = (float*)d_out;

    const int* srcp = ei;
    const int* dstp = ei + N_EDGES;

    // workspace layout
    unsigned short* h1    = (unsigned short*)d_ws;           // [N,256] bf16
    unsigned short* hbuf  = h1   + (size_t)N_NODES*256;      // [N,256] post-ELU bf16
    unsigned short* hml   = hbuf + (size_t)N_NODES*256;      // [N,128] bf16 = [hm|hl]
    unsigned short* W1T   = hml  + (size_t)N_NODES*128;      // [256,128]
    unsigned short* WmlT  = W1T  + 32768;                    // [128,256]
    float* attS2 = (float*)(WmlT + 32768);                   // [128]
    float* attD2 = attS2 + 128;                              // [128]
    float2* as1    = (float2*)(attD2 + 128);                 // ---- zeroed region start
    float2* ad1    = as1  + N_NODES;
    float2* as2    = ad1  + N_NODES;
    float2* ad2    = as2  + N_NODES;
    int*    counts = (int*)(ad2 + N_NODES);                  // ---- zeroed region end
    int*    offsets= counts + N_NODES;
    int*    cursor = offsets + N_NODES;
    int*    bsum   = cursor + N_NODES;                       // [256]
    int*    bscan  = bsum + 256;                             // [256]
    int*    csr_src= bscan + 256;                            // [E]

    const int EB = (N_EDGES + 255) / 256;

    // zero: as1/ad1/as2/ad2 (atomic targets) + counts, contiguous
    hipMemsetAsync(as1, 0, 4*(size_t)N_NODES*sizeof(float2) + N_NODES*sizeof(int), stream);

    // --- CSR build ---
    hist_k<<<EB, 256, 0, stream>>>(dstp, counts);
    breduce_k<<<NB_SCAN, 256, 0, stream>>>(counts, bsum);
    bscan_k<<<1, 256, 0, stream>>>(bsum, bscan);
    scanfinal_k<<<NB_SCAN, 256, 0, stream>>>(counts, bscan, offsets, cursor);
    scatter_k<<<EB, 256, 0, stream>>>(srcp, dstp, cursor, csr_src);

    // --- weight casts + packed att vectors ---
    cast_w_k<<<128, 256, 0, stream>>>(W1, W_mu, W_ls,
                                      att_src_mu, att_src_ls, att_dst_mu, att_dst_ls,
                                      W1T, WmlT, attS2, attD2);

    // --- conv1: h1 = x @ W1 (+ fused att1 logits) ---
    mfma_gemm_k<true><<<dim3(2, 391), 256, 0, stream>>>(x, W1T, h1, N_NODES, 128, 256,
            att_src1, att_dst1, (float*)as1, (float*)ad1, 7);
    agg1_k<<<N_NODES/8, 256, 0, stream>>>(h1, as1, ad1, counts, offsets, csr_src, b1, hbuf);

    // --- conv_mu + conv_ls fused: hml = hbuf @ [W_mu|W_ls] (+ fused att2 logits) ---
    mfma_gemm_k<false><<<dim3(1, 391), 256, 0, stream>>>(hbuf, WmlT, hml, N_NODES, 256, 128,
            attS2, attD2, (float*)as2, (float*)ad2, 6);
    agg2_k<<<N_NODES/16, 256, 0, stream>>>(hml, as2, ad2, counts, offsets, csr_src, b_mu, b_ls, out);
}